// Round 2
// baseline (356.010 us; speedup 1.0000x reference)
//
#include <hip/hip_runtime.h>

// Downsampling_77214922047594 — B=4, N=8192, M=32768, K=16, C=128, G=8, f32 I/O
// Round 5: fused single kernel with HAND-ROLLED grid barrier (plain launch,
// graph-capture-safe). h stays in registers across barriers; GN stats via
// device-scope atomicAdd + acquire readback. No h1/h2/h3 global traffic.

constexpr int NPB = 8192;            // N per batch
constexpr int BN  = 32768;           // total rows
constexpr int CH  = 128;
constexpr int KNB = 16;              // neighbors
constexpr int MS  = 32768;           // s_feats rows per batch
constexpr int NG  = 8;               // groups
constexpr int CG  = 16;              // channels per group
constexpr int RPB = 64;              // rows per block
constexpr int NBLK = BN / RPB;       // 512 blocks == 256 CU x 2 (co-resident)
constexpr int BPB  = NPB / RPB;      // 128 blocks per batch
constexpr int XS = 152;              // LDS stride: 304B rows -> 2-way banks (free)
constexpr int WS = 152;

typedef short short8 __attribute__((ext_vector_type(8)));
typedef float floatx4 __attribute__((ext_vector_type(4)));

static __device__ __forceinline__ unsigned short f2bs(float f) {
    unsigned int u = __builtin_bit_cast(unsigned int, f);
    unsigned int r = (u + 0x7fffu + ((u >> 16) & 1u)) >> 16;   // RNE
    return (unsigned short)r;
}

// Monotonic grid barrier: all NBLK blocks co-resident (512 = 256CU x 2,
// LDS 63KB -> 2/CU, launch_bounds(256,2) -> VGPR<=128). Counter zeroed by
// k_prep each launch, so graph replay is safe.
static __device__ __forceinline__ void gbar(unsigned int* bar, unsigned int target) {
    __syncthreads();                       // waitcnt(0): block's atomics performed
    if (threadIdx.x == 0) {
        __hip_atomic_fetch_add(bar, 1u, __ATOMIC_ACQ_REL, __HIP_MEMORY_SCOPE_AGENT);
        unsigned int v;
        do {
            __builtin_amdgcn_s_sleep(2);
            v = __hip_atomic_load(bar, __ATOMIC_ACQUIRE, __HIP_MEMORY_SCOPE_AGENT);
        } while (v < target);
    }
    __syncthreads();
}

// ---------------- W transpose + bf16 cast + stats/bar zero ----------------
__global__ __launch_bounds__(256) void k_prep(
    const float* __restrict__ W1, const float* __restrict__ W2,
    const float* __restrict__ W3,
    unsigned short* __restrict__ Wt1, unsigned short* __restrict__ Wt2,
    unsigned short* __restrict__ Wt3, float* __restrict__ accs)
{
    const int bi = blockIdx.x;          // 0..191
    if (bi == 0) accs[threadIdx.x] = 0.f;   // 192 stats floats + bar + pad
    const int w  = bi >> 6;
    const int i  = bi & 63;
    const int el = i * 256 + threadIdx.x;
    const int n  = el >> 7, k = el & 127;
    const float* W = (w == 0) ? W1 : (w == 1) ? W2 : W3;
    unsigned short* Wt = (w == 0) ? Wt1 : (w == 1) ? Wt2 : Wt3;
    Wt[n * 128 + k] = f2bs(W[k * 128 + n]);
}

// ---------------- fused kernel ----------------
__global__ __launch_bounds__(256, 2) void k_fused(
    const float* __restrict__ sf, const float* __restrict__ qp,
    const float* __restrict__ sp, const int* __restrict__ idx,
    const float* __restrict__ qf,
    const unsigned short* __restrict__ Wt1,
    const unsigned short* __restrict__ Wt2,
    const unsigned short* __restrict__ Wt3,
    const float* __restrict__ b1, const float* __restrict__ g1, const float* __restrict__ be1,
    const float* __restrict__ b2, const float* __restrict__ g2, const float* __restrict__ be2,
    const float* __restrict__ b3, const float* __restrict__ g3, const float* __restrict__ be3,
    float* __restrict__ accs,           // (3,4,16) zeroed by k_prep
    unsigned int* __restrict__ bar,     // barrier counter, zeroed by k_prep
    float* __restrict__ out)
{
    // XCD swizzle: 2 XCDs per batch -> per-XCD gather working set = one batch
    const int p   = blockIdx.x;
    const int xcd = p & 7, q = p >> 3;                  // q in 0..63
    const int bi  = (xcd >> 1) * BPB + (xcd & 1) * 64 + q;
    const int b   = xcd >> 1;
    const int t   = threadIdx.x;
    const int w   = t >> 6;
    const int l   = t & 63;
    const int lr  = l & 15;
    const int qd  = l >> 4;

    __shared__ unsigned short Xl[RPB * XS];     // 19456 B
    __shared__ unsigned short Wl[CH * WS];      // 38912 B
    __shared__ float2 stats_s[NG];
    __shared__ float wv[RPB * KNB];
    __shared__ float winv[RPB];
    __shared__ float pw[4][16];

    float vals[8][4];                           // pre-GN h tile, lives across barriers

    auto stageW = [&](const unsigned short* __restrict__ Wt) {
        #pragma unroll
        for (int i = 0; i < 8; i++) {
            int el = i * 2048 + t * 8;
            short8 w8 = *(const short8*)(Wt + el);
            *(short8*)&Wl[(el >> 7) * WS + (el & 127)] = w8;
        }
    };

    // MFMA X(64x128)@W(128x128), add bias, keep f32 h in vals, block partials
    // -> 16 device-scope atomicAdds into accL[b*16 + {sum8, sumsq8}]
    auto do_gemm = [&](const float* __restrict__ bias, float* accL) {
        floatx4 acc[8] = {};
        #pragma unroll
        for (int kt = 0; kt < 4; kt++) {
            short8 a = *(const short8*)&Xl[(w * 16 + lr) * XS + kt * 32 + qd * 8];
            #pragma unroll
            for (int j = 0; j < 8; j++) {
                short8 bf = *(const short8*)&Wl[(j * 16 + lr) * WS + kt * 32 + qd * 8];
                acc[j] = __builtin_amdgcn_mfma_f32_16x16x32_bf16(a, bf, acc[j], 0, 0, 0);
            }
        }
        #pragma unroll
        for (int j = 0; j < 8; j++) {
            float bj = bias[j * 16 + lr];
            float ss = 0.f, qq = 0.f;
            #pragma unroll
            for (int r = 0; r < 4; r++) {
                float v = acc[j][r] + bj;
                vals[j][r] = v;
                ss += v; qq += v * v;
            }
            #pragma unroll
            for (int off = 32; off; off >>= 1) {
                ss += __shfl_down(ss, off);
                qq += __shfl_down(qq, off);
            }
            if (l == 0) { pw[w][j] = ss; pw[w][8 + j] = qq; }
        }
        __syncthreads();                         // all waves done with Wl/Xl + pw ready
        if (t < 16)
            atomicAdd(&accL[b * 16 + t], pw[0][t] + pw[1][t] + pw[2][t] + pw[3][t]);
    };

    // stats readback (after gbar) + GN + LeakyReLU (+resid) -> bf16 Xl
    auto gn_apply = [&](float* accL, const float* __restrict__ g,
                        const float* __restrict__ be, const float* __restrict__ resid) {
        if (t < 8) {
            float s  = __hip_atomic_load(accL + b * 16 + t,     __ATOMIC_ACQUIRE, __HIP_MEMORY_SCOPE_AGENT);
            float q2 = __hip_atomic_load(accL + b * 16 + 8 + t, __ATOMIC_ACQUIRE, __HIP_MEMORY_SCOPE_AGENT);
            const float cnt = (float)(NPB * CG);
            float mean = s / cnt;
            float var  = q2 / cnt - mean * mean;
            stats_s[t] = make_float2(mean, rsqrtf(var + 1e-5f));
        }
        __syncthreads();
        #pragma unroll
        for (int j = 0; j < 8; j++) {
            const int c = j * 16 + lr;
            float2 st = stats_s[j];
            float ga = g[c], bb = be[c];
            #pragma unroll
            for (int r = 0; r < 4; r++) {
                float y = (vals[j][r] - st.x) * st.y * ga + bb;
                y = (y >= 0.f) ? y : 0.1f * y;
                if (resid)
                    y += resid[((size_t)bi * RPB + w * 16 + qd * 4 + r) * CH + c];
                Xl[(w * 16 + qd * 4 + r) * XS + c] = f2bs(y);
            }
        }
        __syncthreads();                         // Xl ready for MFMA
    };

    // ---------------- phase A: W1 stage + IDW gather -> Xl ----------------
    stageW(Wt1);
    #pragma unroll
    for (int i = 0; i < 4; i++) {
        int pk = i * 256 + t;                    // (row, k) pair index
        int row = pk >> 4, k = pk & 15;
        size_t rg = (size_t)bi * RPB + row;
        float qx = qp[rg * 3 + 0], qy = qp[rg * 3 + 1], qz = qp[rg * 3 + 2];
        const float* spp = sp + (rg * KNB + k) * 3;
        float dx = spp[0] - qx, dy = spp[1] - qy, dz = spp[2] - qz;
        wv[pk] = 1.0f / (dx * dx + dy * dy + dz * dz + 1e-8f);
    }
    __syncthreads();
    if (t < RPB) {
        float s = 0.f;
        #pragma unroll
        for (int k = 0; k < KNB; k++) s += wv[t * KNB + k];
        winv[t] = 1.0f / s;
    }
    __syncthreads();
    {
        const int grp = t >> 5, c4 = (t & 31) * 4;
        for (int rr = 0; rr < 8; rr++) {
            int row = grp * 8 + rr;
            size_t rg = (size_t)bi * RPB + row;
            const int* ip = idx + rg * KNB;
            float ax = 0.f, ay = 0.f, az = 0.f, aw = 0.f;
            #pragma unroll
            for (int k = 0; k < KNB; k++) {
                int j = ip[k];
                const float4 f = *(const float4*)(sf + ((size_t)b * MS + j) * CH + c4);
                float ww = wv[row * KNB + k];
                ax += ww * f.x; ay += ww * f.y; az += ww * f.z; aw += ww * f.w;
            }
            float wi = winv[row];
            ushort4 pkv;
            pkv.x = f2bs(ax * wi); pkv.y = f2bs(ay * wi);
            pkv.z = f2bs(az * wi); pkv.w = f2bs(aw * wi);
            *(ushort4*)&Xl[row * XS + c4] = pkv;
        }
    }
    __syncthreads();

    // ---------------- layer 1 ----------------
    do_gemm(b1, accs + 0);
    stageW(Wt2);                                 // prefetch W2 under the barrier wait
    gbar(bar, 1 * NBLK);

    // ---------------- layer 2 ----------------
    gn_apply(accs + 0, g1, be1, nullptr);
    do_gemm(b2, accs + 64);
    stageW(Wt3);
    gbar(bar, 2 * NBLK);

    // ---------------- layer 3 (with residual) ----------------
    gn_apply(accs + 64, g2, be2, qf);
    do_gemm(b3, accs + 128);
    gbar(bar, 3 * NBLK);

    // ---------------- final GN + LeakyReLU -> f32 out ----------------
    if (t < 8) {
        float s  = __hip_atomic_load(accs + 128 + b * 16 + t,     __ATOMIC_ACQUIRE, __HIP_MEMORY_SCOPE_AGENT);
        float q2 = __hip_atomic_load(accs + 128 + b * 16 + 8 + t, __ATOMIC_ACQUIRE, __HIP_MEMORY_SCOPE_AGENT);
        const float cnt = (float)(NPB * CG);
        float mean = s / cnt;
        float var  = q2 / cnt - mean * mean;
        stats_s[t] = make_float2(mean, rsqrtf(var + 1e-5f));
    }
    __syncthreads();
    #pragma unroll
    for (int j = 0; j < 8; j++) {
        const int c = j * 16 + lr;
        float2 st = stats_s[j];
        float ga = g3[c], bb = be3[c];
        #pragma unroll
        for (int r = 0; r < 4; r++) {
            float y = (vals[j][r] - st.x) * st.y * ga + bb;
            y = (y >= 0.f) ? y : 0.1f * y;
            out[((size_t)bi * RPB + w * 16 + qd * 4 + r) * CH + c] = y;
        }
    }
}

extern "C" void kernel_launch(void* const* d_in, const int* in_sizes, int n_in,
                              void* d_out, int out_size, void* d_ws, size_t ws_size,
                              hipStream_t stream) {
    const float* qf  = (const float*)d_in[0];
    const float* sf  = (const float*)d_in[1];
    const float* qp  = (const float*)d_in[2];
    const float* sp  = (const float*)d_in[3];
    const int*   idx = (const int*)  d_in[4];
    const float* W1  = (const float*)d_in[5];
    const float* b1  = (const float*)d_in[6];
    const float* g1  = (const float*)d_in[7];
    const float* be1 = (const float*)d_in[8];
    const float* W2  = (const float*)d_in[9];
    const float* b2  = (const float*)d_in[10];
    const float* g2  = (const float*)d_in[11];
    const float* be2 = (const float*)d_in[12];
    const float* W3  = (const float*)d_in[13];
    const float* b3  = (const float*)d_in[14];
    const float* g3  = (const float*)d_in[15];
    const float* be3 = (const float*)d_in[16];

    char* ws = (char*)d_ws;
    unsigned short* Wt1 = (unsigned short*)(ws);
    unsigned short* Wt2 = (unsigned short*)(ws + 32768);
    unsigned short* Wt3 = (unsigned short*)(ws + 65536);
    float* accs = (float*)(ws + 98304);          // 192 stats floats
    unsigned int* bar = (unsigned int*)(ws + 98304 + 192 * 4);
    float* out = (float*)d_out;

    k_prep<<<192, 256, 0, stream>>>(W1, W2, W3, Wt1, Wt2, Wt3, accs);
    k_fused<<<NBLK, 256, 0, stream>>>(sf, qp, sp, idx, qf,
                                      Wt1, Wt2, Wt3,
                                      b1, g1, be1,
                                      b2, g2, be2,
                                      b3, g3, be3,
                                      accs, bar, out);
}

// Round 4
// 307.621 us; speedup vs baseline: 1.1573x; 1.1573x over previous
//
#include <hip/hip_runtime.h>

// Downsampling_77214922047594 — B=4, N=8192, M=32768, K=16, C=128, G=8, f32 I/O
// Round 7: fused kernel = round-2 (passing) memory semantics + contention fixes:
//  - stats: 8 replicas, 256 B apart (atomic contention /8); ACQUIRE readback
//  - arrival: 8 sub-counters (128 B apart) + global counter (two-level)
//  - poll: RELAXED load on a dedicated release-flag line, s_sleep(8) cadence,
//    t0 acquire fence on exit (readback loads are acquire anyway)
//  - gather: round-2 simple loop (proven)

constexpr int NPB = 8192;            // N per batch
constexpr int BN  = 32768;           // total rows
constexpr int CH  = 128;
constexpr int KNB = 16;              // neighbors
constexpr int MS  = 32768;           // s_feats rows per batch
constexpr int NG  = 8;               // groups
constexpr int CG  = 16;              // channels per group
constexpr int RPB = 64;              // rows per block
constexpr int NBLK = BN / RPB;       // 512 blocks == 256 CU x 2 (co-resident)
constexpr int BPB  = NPB / RPB;      // 128 blocks per batch
constexpr int SUBN = NBLK / 8;       // arrivals per sub-counter
constexpr int XS = 152;              // LDS stride: 304B rows -> 2-way banks (free)
constexpr int WS = 152;

// ctl region (u32 index from ctl base, zeroed range [0,2048)):
//   stats replicas: [0, 1536)       = 3 layers * 8 replicas * 64 floats
//   sub-counters:   1536 + r*32     (128 B apart), r=0..7
//   global counter: 1792
//   release flag:   1824

typedef short short8 __attribute__((ext_vector_type(8)));
typedef float floatx4 __attribute__((ext_vector_type(4)));

static __device__ __forceinline__ unsigned short f2bs(float f) {
    unsigned int u = __builtin_bit_cast(unsigned int, f);
    unsigned int r = (u + 0x7fffu + ((u >> 16) & 1u)) >> 16;   // RNE
    return (unsigned short)r;
}

// ---------------- W transpose + bf16 cast + ctl zero ----------------
__global__ __launch_bounds__(256) void k_prep(
    const float* __restrict__ W1, const float* __restrict__ W2,
    const float* __restrict__ W3,
    unsigned short* __restrict__ Wt1, unsigned short* __restrict__ Wt2,
    unsigned short* __restrict__ Wt3, unsigned int* __restrict__ ctl)
{
    const int bi = blockIdx.x;          // 0..191
    if (bi == 0) {
        #pragma unroll
        for (int i = 0; i < 8; i++) ctl[threadIdx.x * 8 + i] = 0u;
    }
    const int w  = bi >> 6;
    const int i  = bi & 63;
    const int el = i * 256 + threadIdx.x;
    const int n  = el >> 7, k = el & 127;
    const float* W = (w == 0) ? W1 : (w == 1) ? W2 : W3;
    unsigned short* Wt = (w == 0) ? Wt1 : (w == 1) ? Wt2 : Wt3;
    Wt[n * 128 + k] = f2bs(W[k * 128 + n]);
}

// ---------------- fused kernel ----------------
__global__ __launch_bounds__(256, 2) void k_fused(
    const float* __restrict__ sf, const float* __restrict__ qp,
    const float* __restrict__ sp, const int* __restrict__ idx,
    const float* __restrict__ qf,
    const unsigned short* __restrict__ Wt1,
    const unsigned short* __restrict__ Wt2,
    const unsigned short* __restrict__ Wt3,
    const float* __restrict__ b1, const float* __restrict__ g1, const float* __restrict__ be1,
    const float* __restrict__ b2, const float* __restrict__ g2, const float* __restrict__ be2,
    const float* __restrict__ b3, const float* __restrict__ g3, const float* __restrict__ be3,
    float* __restrict__ ctlf,           // ctl base, zeroed by k_prep
    float* __restrict__ out)
{
    float* stats = ctlf;                               // 3*8*64 floats
    unsigned int* subs = (unsigned int*)(ctlf + 1536); // sub r at subs[r*32]
    unsigned int* gcnt = subs + 256;
    unsigned int* flag = subs + 288;

    // XCD swizzle: 2 XCDs per batch -> per-XCD gather working set = one batch
    const int p   = blockIdx.x;
    const int rep = p & 7;
    const int q   = p >> 3;                            // 0..63
    const int bi  = (rep >> 1) * BPB + (rep & 1) * 64 + q;
    const int b   = rep >> 1;
    const int t   = threadIdx.x;
    const int w   = t >> 6;
    const int l   = t & 63;
    const int lr  = l & 15;
    const int qd  = l >> 4;

    __shared__ unsigned short Xl[RPB * XS];     // 19456 B
    __shared__ unsigned short Wl[CH * WS];      // 38912 B
    __shared__ float2 stats_s[NG];
    __shared__ float red16[16];
    __shared__ float wv[RPB * KNB];
    __shared__ float winv[RPB];
    __shared__ float pw[4][16];

    float vals[8][4];                           // pre-GN h tile, lives across barriers

    auto stageW = [&](const unsigned short* __restrict__ Wt) {
        #pragma unroll
        for (int i = 0; i < 8; i++) {
            int el = i * 2048 + t * 8;
            short8 w8 = *(const short8*)(Wt + el);
            *(short8*)&Wl[(el >> 7) * WS + (el & 127)] = w8;
        }
    };

    // two-level arrival + relaxed-poll release flag; phase = 1,2,3
    auto gbar = [&](unsigned int phase) {
        __syncthreads();                  // drains vmcnt: block's atomics performed
        if (t == 0) {
            unsigned int so = __hip_atomic_fetch_add(subs + rep * 32, 1u,
                                 __ATOMIC_ACQ_REL, __HIP_MEMORY_SCOPE_AGENT);
            if (so == phase * SUBN - 1) {
                unsigned int go = __hip_atomic_fetch_add(gcnt, 1u,
                                     __ATOMIC_ACQ_REL, __HIP_MEMORY_SCOPE_AGENT);
                if (go == phase * 8 - 1)
                    __hip_atomic_store(flag, phase, __ATOMIC_RELEASE,
                                       __HIP_MEMORY_SCOPE_AGENT);
            }
            unsigned int v = __hip_atomic_load(flag, __ATOMIC_RELAXED,
                                               __HIP_MEMORY_SCOPE_AGENT);
            while (v < phase) {
                __builtin_amdgcn_s_sleep(8);
                v = __hip_atomic_load(flag, __ATOMIC_RELAXED,
                                      __HIP_MEMORY_SCOPE_AGENT);
            }
            __builtin_amdgcn_fence(__ATOMIC_ACQUIRE, "agent");
        }
        __syncthreads();
    };

    // MFMA X(64x128)@W(128x128), bias, keep f32 h in vals, block partials
    // -> 16 atomicAdds into this block's replica of layer L's stats
    auto do_gemm = [&](const float* __restrict__ bias, int L) {
        floatx4 acc[8] = {};
        #pragma unroll
        for (int kt = 0; kt < 4; kt++) {
            short8 a = *(const short8*)&Xl[(w * 16 + lr) * XS + kt * 32 + qd * 8];
            #pragma unroll
            for (int j = 0; j < 8; j++) {
                short8 bf = *(const short8*)&Wl[(j * 16 + lr) * WS + kt * 32 + qd * 8];
                acc[j] = __builtin_amdgcn_mfma_f32_16x16x32_bf16(a, bf, acc[j], 0, 0, 0);
            }
        }
        #pragma unroll
        for (int j = 0; j < 8; j++) {
            float bj = bias[j * 16 + lr];
            float ss = 0.f, qq = 0.f;
            #pragma unroll
            for (int r = 0; r < 4; r++) {
                float v = acc[j][r] + bj;
                vals[j][r] = v;
                ss += v; qq += v * v;
            }
            #pragma unroll
            for (int off = 32; off; off >>= 1) {
                ss += __shfl_down(ss, off);
                qq += __shfl_down(qq, off);
            }
            if (l == 0) { pw[w][j] = ss; pw[w][8 + j] = qq; }
        }
        __syncthreads();                  // waves done with Wl/Xl + pw ready
        if (t < 16)
            atomicAdd(stats + (L * 8 + rep) * 64 + b * 16 + t,
                      pw[0][t] + pw[1][t] + pw[2][t] + pw[3][t]);
    };

    // stats readback (sum 8 replicas, ACQUIRE) -> GN + LeakyReLU (+resid) -> Xl
    auto gn_apply = [&](int L, const float* __restrict__ g,
                        const float* __restrict__ be, const float* __restrict__ resid) {
        if (t < 16) {
            float s = 0.f;
            #pragma unroll
            for (int r = 0; r < 8; r++)
                s += __hip_atomic_load(stats + (L * 8 + r) * 64 + b * 16 + t,
                                       __ATOMIC_ACQUIRE, __HIP_MEMORY_SCOPE_AGENT);
            red16[t] = s;
        }
        __syncthreads();
        if (t < NG) {
            const float cnt = (float)(NPB * CG);
            float mean = red16[t] / cnt;
            float var  = red16[t + 8] / cnt - mean * mean;
            stats_s[t] = make_float2(mean, rsqrtf(var + 1e-5f));
        }
        __syncthreads();
        #pragma unroll
        for (int j = 0; j < 8; j++) {
            const int c = j * 16 + lr;
            float2 st = stats_s[j];
            float ga = g[c], bb = be[c];
            #pragma unroll
            for (int r = 0; r < 4; r++) {
                float y = (vals[j][r] - st.x) * st.y * ga + bb;
                y = (y >= 0.f) ? y : 0.1f * y;
                if (resid)
                    y += resid[((size_t)bi * RPB + w * 16 + qd * 4 + r) * CH + c];
                Xl[(w * 16 + qd * 4 + r) * XS + c] = f2bs(y);
            }
        }
        __syncthreads();                  // Xl ready for MFMA
    };

    // ---------------- phase A: W1 stage + IDW gather -> Xl ----------------
    stageW(Wt1);
    #pragma unroll
    for (int i = 0; i < 4; i++) {
        int pk = i * 256 + t;                    // (row, k) pair index
        int row = pk >> 4, k = pk & 15;
        size_t rg = (size_t)bi * RPB + row;
        float qx = qp[rg * 3 + 0], qy = qp[rg * 3 + 1], qz = qp[rg * 3 + 2];
        const float* spp = sp + (rg * KNB + k) * 3;
        float dx = spp[0] - qx, dy = spp[1] - qy, dz = spp[2] - qz;
        wv[pk] = 1.0f / (dx * dx + dy * dy + dz * dz + 1e-8f);
    }
    __syncthreads();
    if (t < RPB) {
        float s = 0.f;
        #pragma unroll
        for (int k = 0; k < KNB; k++) s += wv[t * KNB + k];
        winv[t] = 1.0f / s;
    }
    __syncthreads();
    {
        const int grp = t >> 5, c4 = (t & 31) * 4;
        for (int rr = 0; rr < 8; rr++) {
            int row = grp * 8 + rr;
            size_t rg = (size_t)bi * RPB + row;
            const int* ip = idx + rg * KNB;
            float ax = 0.f, ay = 0.f, az = 0.f, aw = 0.f;
            #pragma unroll
            for (int k = 0; k < KNB; k++) {
                int j = ip[k];
                const float4 f = *(const float4*)(sf + ((size_t)b * MS + j) * CH + c4);
                float ww = wv[row * KNB + k];
                ax += ww * f.x; ay += ww * f.y; az += ww * f.z; aw += ww * f.w;
            }
            float wi = winv[row];
            ushort4 pkv;
            pkv.x = f2bs(ax * wi); pkv.y = f2bs(ay * wi);
            pkv.z = f2bs(az * wi); pkv.w = f2bs(aw * wi);
            *(ushort4*)&Xl[row * XS + c4] = pkv;
        }
    }
    __syncthreads();

    // ---------------- layer 1 ----------------
    do_gemm(b1, 0);
    stageW(Wt2);                                 // prefetch W2 under the barrier wait
    gbar(1);

    // ---------------- layer 2 ----------------
    gn_apply(0, g1, be1, nullptr);
    do_gemm(b2, 1);
    stageW(Wt3);
    gbar(2);

    // ---------------- layer 3 (with residual) ----------------
    gn_apply(1, g2, be2, qf);
    do_gemm(b3, 2);
    gbar(3);

    // ---------------- final GN + LeakyReLU -> f32 out ----------------
    if (t < 16) {
        float s = 0.f;
        #pragma unroll
        for (int r = 0; r < 8; r++)
            s += __hip_atomic_load(stats + (2 * 8 + r) * 64 + b * 16 + t,
                                   __ATOMIC_ACQUIRE, __HIP_MEMORY_SCOPE_AGENT);
        red16[t] = s;
    }
    __syncthreads();
    if (t < NG) {
        const float cnt = (float)(NPB * CG);
        float mean = red16[t] / cnt;
        float var  = red16[t + 8] / cnt - mean * mean;
        stats_s[t] = make_float2(mean, rsqrtf(var + 1e-5f));
    }
    __syncthreads();
    #pragma unroll
    for (int j = 0; j < 8; j++) {
        const int c = j * 16 + lr;
        float2 st = stats_s[j];
        float ga = g3[c], bb = be3[c];
        #pragma unroll
        for (int r = 0; r < 4; r++) {
            float y = (vals[j][r] - st.x) * st.y * ga + bb;
            y = (y >= 0.f) ? y : 0.1f * y;
            out[((size_t)bi * RPB + w * 16 + qd * 4 + r) * CH + c] = y;
        }
    }
}

extern "C" void kernel_launch(void* const* d_in, const int* in_sizes, int n_in,
                              void* d_out, int out_size, void* d_ws, size_t ws_size,
                              hipStream_t stream) {
    const float* qf  = (const float*)d_in[0];
    const float* sf  = (const float*)d_in[1];
    const float* qp  = (const float*)d_in[2];
    const float* sp  = (const float*)d_in[3];
    const int*   idx = (const int*)  d_in[4];
    const float* W1  = (const float*)d_in[5];
    const float* b1  = (const float*)d_in[6];
    const float* g1  = (const float*)d_in[7];
    const float* be1 = (const float*)d_in[8];
    const float* W2  = (const float*)d_in[9];
    const float* b2  = (const float*)d_in[10];
    const float* g2  = (const float*)d_in[11];
    const float* be2 = (const float*)d_in[12];
    const float* W3  = (const float*)d_in[13];
    const float* b3  = (const float*)d_in[14];
    const float* g3  = (const float*)d_in[15];
    const float* be3 = (const float*)d_in[16];

    char* ws = (char*)d_ws;
    unsigned short* Wt1 = (unsigned short*)(ws);
    unsigned short* Wt2 = (unsigned short*)(ws + 32768);
    unsigned short* Wt3 = (unsigned short*)(ws + 65536);
    float* ctlf = (float*)(ws + 98304);          // 2048-u32 ctl region
    float* out = (float*)d_out;

    k_prep<<<192, 256, 0, stream>>>(W1, W2, W3, Wt1, Wt2, Wt3,
                                    (unsigned int*)ctlf);
    k_fused<<<NBLK, 256, 0, stream>>>(sf, qp, sp, idx, qf,
                                      Wt1, Wt2, Wt3,
                                      b1, g1, be1,
                                      b2, g2, be2,
                                      b3, g3, be3,
                                      ctlf, out);
}